// Round 5
// baseline (1591.979 us; speedup 1.0000x reference)
//
#include <hip/hip_runtime.h>
#include <hip/hip_bf16.h>

// MoE SwiGLU: H=2048, I=1408, E=8, TOPK=2, T=4096 tokens (8192 pairs).
// R5: 256x256 tiles (4x work per barrier-drain), all-register staging with
// in-loop f32->bf16 convert (no cvt pass, no global_load_lds aliasing hazards),
// double-buffered LDS, loads issued early inside the iteration.

typedef __bf16 bf16;
typedef bf16 bf16x8 __attribute__((ext_vector_type(8)));
typedef float f32x4 __attribute__((ext_vector_type(4)));

constexpr int Hdim = 2048;
constexpr int Idim = 1408;
constexpr int NE = 8;
constexpr int TOPK = 2;
constexpr int NPAIR = 8192;   // T * TOPK
constexpr int BK = 64;

// ---------------- binning (deterministic) ----------------

__global__ void k_bin1(const int* __restrict__ eidx, int* __restrict__ chunkhist) {
    __shared__ int h[NE];
    int t = threadIdx.x;
    if (t < NE) h[t] = 0;
    __syncthreads();
    int p = blockIdx.x * 256 + t;
    atomicAdd(&h[eidx[p]], 1);
    __syncthreads();
    if (t < NE) chunkhist[blockIdx.x * NE + t] = h[t];
}

__global__ void k_bin2(int* __restrict__ meta, const int* __restrict__ chunkhist,
                       int* __restrict__ chunkbase) {
    if (threadIdx.x == 0) {
        int counts[NE];
        for (int e = 0; e < NE; e++) counts[e] = 0;
        for (int b = 0; b < 32; b++)
            for (int e = 0; e < NE; e++) {
                chunkbase[b * NE + e] = counts[e];
                counts[e] += chunkhist[b * NE + e];
            }
        int acc = 0;
        for (int e = 0; e < NE; e++) {
            meta[e] = counts[e];      // counts
            meta[8 + e] = acc;        // exclusive offsets
            acc += counts[e];
        }
    }
}

__global__ void k_bin3(const int* __restrict__ eidx, const float* __restrict__ wts,
                       const int* __restrict__ meta, const int* __restrict__ chunkbase,
                       int* __restrict__ token_id, float* __restrict__ weightv) {
    __shared__ int earr[256];
    int t = threadIdx.x;
    int p = blockIdx.x * 256 + t;
    int e = eidx[p];
    earr[t] = e;
    __syncthreads();
    int rank = 0;
    for (int q = 0; q < t; q++) rank += (earr[q] == e) ? 1 : 0;
    int pos = meta[8 + e] + chunkbase[blockIdx.x * NE + e] + rank;
    token_id[pos] = p / TOPK;
    weightv[pos] = wts[p];
}

// ---------------- GEMM1: gu = X_e * w13[e]^T, fused SwiGLU ----------------
// Block: 256M x 256N where the 256 B-rows interleave 16 gate / 16 up rows so
// SwiGLU pairs land in the same lane (frag n=even: gate, n+1: same-col up).
// 512 threads = 8 waves (2Mr x 4Nc), wave tile 128x64, acc[8][4].
// grid: x = 32 m-tiles (early exit), y = 11 (128 h-cols each), z = 8 experts.

__global__ __launch_bounds__(512, 1) void k_gemm1(
    const float* __restrict__ x, const float* __restrict__ w13,
    const int* __restrict__ meta, bf16* __restrict__ hact) {
    const int e = blockIdx.z;
    const int n_e = meta[e];
    const int m0 = blockIdx.x * 256;
    if (m0 >= n_e) return;
    const int base = meta[8 + e];
    const int* toks = (const int*)(meta + 64) + base;
    const float* wg = w13 + (size_t)e * (2 * Idim) * Hdim + (size_t)(blockIdx.y * 128) * Hdim;
    const float* wu = wg + (size_t)Idim * Hdim;

    // buffer: A[256*64] @ elem 0, B[256*64] @ elem 16384; dbuf stride 32768 elems
    __shared__ bf16 smem[2 * 32768];

    const int tid = threadIdx.x;
    const int lane = tid & 63;
    const int wid = tid >> 6;
    const int wr = wid >> 2, wc = wid & 3;
    const int l16 = lane & 15, lq = lane >> 4;
    const int xr = (lq) ^ (l16 & 7);          // kk=0 chunk xor base
    const int xr1 = (4 + lq) ^ (l16 & 7);     // kk=1

    // staging: each matrix tile = 2048 chunks of 16B; thread handles 4 chunks
    // (s = r*512 + tid). LDS offset = row*128 + (c ^ (row&7))*16 (XOR swizzle).
    const float* gA[4]; int wA[4];
    const float* gB[4]; int wB[4];
#pragma unroll
    for (int r = 0; r < 4; r++) {
        int s = r * 512 + tid;
        int row = s >> 3, c = s & 7;
        int wo = row * 128 + ((c ^ (row & 7)) * 16);
        wA[r] = wo;
        wB[r] = 32768 + wo;                   // B at byte 32768 within buffer
        int rr = m0 + row;
        if (rr >= n_e) rr = n_e - 1;          // clamp keeps reads in-bounds
        gA[r] = x + (size_t)toks[rr] * Hdim + c * 8;
        int gr = ((row >> 5) * 16) + (row & 15);   // gate/up source row in col-block
        const float* bsrc = (row & 16) ? wu : wg;
        gB[r] = bsrc + (size_t)(blockIdx.y * 0 + gr) * Hdim + c * 8;
    }

    f32x4 acc[8][4];
#pragma unroll
    for (int m = 0; m < 8; m++)
#pragma unroll
        for (int n = 0; n < 4; n++) acc[m][n] = f32x4{0.f, 0.f, 0.f, 0.f};

#define LOAD_F32(RG, GP, K0)                                                \
    _Pragma("unroll")                                                       \
    for (int r = 0; r < 4; r++) {                                           \
        RG[r][0] = *reinterpret_cast<const f32x4*>(GP[r] + (K0));           \
        RG[r][1] = *reinterpret_cast<const f32x4*>(GP[r] + (K0) + 4);       \
    }

#define CVT_WRITE(RG, WO, CUR)                                              \
    _Pragma("unroll")                                                       \
    for (int r = 0; r < 4; r++) {                                           \
        bf16x8 v;                                                           \
        _Pragma("unroll")                                                   \
        for (int j = 0; j < 4; j++) {                                       \
            v[j] = (bf16)RG[r][0][j];                                       \
            v[4 + j] = (bf16)RG[r][1][j];                                   \
        }                                                                   \
        *reinterpret_cast<bf16x8*>((char*)smem + (CUR) * 65536 + WO[r]) = v;\
    }

    // prologue: stage tile 0 into buffer 0
    {
        f32x4 ra[4][2], rb[4][2];
        LOAD_F32(ra, gA, 0);
        LOAD_F32(rb, gB, 0);
        CVT_WRITE(ra, wA, 0);
        CVT_WRITE(rb, wB, 0);
    }
    __syncthreads();

    int cur = 0;
    constexpr int NITER = Hdim / BK;   // 32
    for (int t = 0; t < NITER; ++t) {
        const bf16* As = smem + cur * 32768;
        const bf16* Bs = As + 16384;
        const int kn = (t + 1) * BK;
        f32x4 ra[4][2], rb[4][2];
        if (t + 1 < NITER) { LOAD_F32(ra, gA, kn); }   // A prefetch in flight

        // kk = 0
        {
            bf16x8 af[8], bf[4];
#pragma unroll
            for (int m = 0; m < 8; m++) {
                int row = wr * 128 + m * 16 + l16;
                af[m] = *reinterpret_cast<const bf16x8*>(&As[row * 64 + xr * 8]);
            }
#pragma unroll
            for (int n = 0; n < 4; n++) {
                int row = wc * 64 + n * 16 + l16;
                bf[n] = *reinterpret_cast<const bf16x8*>(&Bs[row * 64 + xr * 8]);
            }
#pragma unroll
            for (int m = 0; m < 8; m++)
#pragma unroll
                for (int n = 0; n < 4; n++)
                    acc[m][n] = __builtin_amdgcn_mfma_f32_16x16x32_bf16(af[m], bf[n], acc[m][n], 0, 0, 0);
        }

        if (t + 1 < NITER) {
            CVT_WRITE(ra, wA, cur ^ 1);                // consume A loads
            LOAD_F32(rb, gB, kn);                      // B prefetch in flight
        }

        // kk = 1
        {
            bf16x8 af[8], bf[4];
#pragma unroll
            for (int m = 0; m < 8; m++) {
                int row = wr * 128 + m * 16 + l16;
                af[m] = *reinterpret_cast<const bf16x8*>(&As[row * 64 + xr1 * 8]);
            }
#pragma unroll
            for (int n = 0; n < 4; n++) {
                int row = wc * 64 + n * 16 + l16;
                bf[n] = *reinterpret_cast<const bf16x8*>(&Bs[row * 64 + xr1 * 8]);
            }
#pragma unroll
            for (int m = 0; m < 8; m++)
#pragma unroll
                for (int n = 0; n < 4; n++)
                    acc[m][n] = __builtin_amdgcn_mfma_f32_16x16x32_bf16(af[m], bf[n], acc[m][n], 0, 0, 0);
        }

        if (t + 1 < NITER) { CVT_WRITE(rb, wB, cur ^ 1); }
        __syncthreads();
        cur ^= 1;
    }

    // epilogue: h = silu(g)*u. frag n=2p is gate cols, n=2p+1 the matching up.
    // h col = by*128 + wc*32 + p*16 + l16. C layout: col=lane&15, row=lq*4+j.
    const int colbase = blockIdx.y * 128 + wc * 32;
#pragma unroll
    for (int m = 0; m < 8; m++) {
        int lr0 = m0 + wr * 128 + m * 16 + lq * 4;
#pragma unroll
        for (int j = 0; j < 4; j++) {
            int lr = lr0 + j;
            if (lr < n_e) {
                size_t rowoff = (size_t)(base + lr) * Idim;
#pragma unroll
                for (int p = 0; p < 2; p++) {
                    float g = acc[m][2 * p][j], u = acc[m][2 * p + 1][j];
                    float v = (g / (1.f + __expf(-g))) * u;
                    hact[rowoff + colbase + p * 16 + l16] = (bf16)v;
                }
            }
        }
    }
#undef LOAD_F32
#undef CVT_WRITE
}

// ---------------- GEMM2: y = hact * down_proj[e]^T, weighted scatter-add ----------------
// 256M x 256N, 512 threads, dbuf 128KB. A = hact (bf16, direct copy), B = down (f32, cvt).
// grid: x = 32 m-tiles (early exit), y = 8 H col tiles, z = 8 experts -> 256 active blocks.

__global__ __launch_bounds__(512, 1) void k_gemm2(
    const bf16* __restrict__ hact, const float* __restrict__ dproj,
    const int* __restrict__ meta, const float* __restrict__ weightv,
    float* __restrict__ out) {
    const int e = blockIdx.z;
    const int n_e = meta[e];
    const int m0 = blockIdx.x * 256;
    if (m0 >= n_e) return;
    const int base = meta[8 + e];
    const int* toks = (const int*)(meta + 64) + base;
    const float* wb = dproj + (size_t)e * Hdim * Idim + (size_t)(blockIdx.y * 256) * Idim;

    __shared__ bf16 smem[2 * 32768];

    const int tid = threadIdx.x;
    const int lane = tid & 63;
    const int wid = tid >> 6;
    const int wr = wid >> 2, wc = wid & 3;
    const int l16 = lane & 15, lq = lane >> 4;
    const int xr = (lq) ^ (l16 & 7);
    const int xr1 = (4 + lq) ^ (l16 & 7);

    const bf16* gA[4]; int wA[4];
    const float* gB[4]; int wB[4];
#pragma unroll
    for (int r = 0; r < 4; r++) {
        int s = r * 512 + tid;
        int row = s >> 3, c = s & 7;
        int wo = row * 128 + ((c ^ (row & 7)) * 16);
        wA[r] = wo;
        wB[r] = 32768 + wo;
        int rr = m0 + row;
        if (rr >= n_e) rr = n_e - 1;
        gA[r] = hact + (size_t)(base + rr) * Idim + c * 8;
        gB[r] = wb + (size_t)row * Idim + c * 8;
    }

    f32x4 acc[8][4];
#pragma unroll
    for (int m = 0; m < 8; m++)
#pragma unroll
        for (int n = 0; n < 4; n++) acc[m][n] = f32x4{0.f, 0.f, 0.f, 0.f};

#define LOAD_BF16(RG, GP, K0)                                               \
    _Pragma("unroll")                                                       \
    for (int r = 0; r < 4; r++)                                             \
        RG[r] = *reinterpret_cast<const bf16x8*>(GP[r] + (K0));

#define WRITE_BF16(RG, WO, CUR)                                             \
    _Pragma("unroll")                                                       \
    for (int r = 0; r < 4; r++)                                             \
        *reinterpret_cast<bf16x8*>((char*)smem + (CUR) * 65536 + WO[r]) = RG[r];

#define LOAD_F32B(RG, GP, K0)                                               \
    _Pragma("unroll")                                                       \
    for (int r = 0; r < 4; r++) {                                           \
        RG[r][0] = *reinterpret_cast<const f32x4*>(GP[r] + (K0));           \
        RG[r][1] = *reinterpret_cast<const f32x4*>(GP[r] + (K0) + 4);       \
    }

#define CVT_WRITEB(RG, WO, CUR)                                             \
    _Pragma("unroll")                                                       \
    for (int r = 0; r < 4; r++) {                                           \
        bf16x8 v;                                                           \
        _Pragma("unroll")                                                   \
        for (int j = 0; j < 4; j++) {                                       \
            v[j] = (bf16)RG[r][0][j];                                       \
            v[4 + j] = (bf16)RG[r][1][j];                                   \
        }                                                                   \
        *reinterpret_cast<bf16x8*>((char*)smem + (CUR) * 65536 + WO[r]) = v;\
    }

    {
        bf16x8 ra[4]; f32x4 rb[4][2];
        LOAD_BF16(ra, gA, 0);
        LOAD_F32B(rb, gB, 0);
        WRITE_BF16(ra, wA, 0);
        CVT_WRITEB(rb, wB, 0);
    }
    __syncthreads();

    int cur = 0;
    constexpr int NITER = Idim / BK;   // 22
    for (int t = 0; t < NITER; ++t) {
        const bf16* As = smem + cur * 32768;
        const bf16* Bs = As + 16384;
        const int kn = (t + 1) * BK;
        bf16x8 ra[4]; f32x4 rb[4][2];
        if (t + 1 < NITER) { LOAD_BF16(ra, gA, kn); }

        // kk = 0
        {
            bf16x8 af[8], bf[4];
#pragma unroll
            for (int m = 0; m < 8; m++) {
                int row = wr * 128 + m * 16 + l16;
                af[m] = *reinterpret_cast<const bf16x8*>(&As[row * 64 + xr * 8]);
            }
#pragma unroll
            for (int n = 0; n < 4; n++) {
                int row = wc * 64 + n * 16 + l16;
                bf[n] = *reinterpret_cast<const bf16x8*>(&Bs[row * 64 + xr * 8]);
            }
#pragma unroll
            for (int m = 0; m < 8; m++)
#pragma unroll
                for (int n = 0; n < 4; n++)
                    acc[m][n] = __builtin_amdgcn_mfma_f32_16x16x32_bf16(af[m], bf[n], acc[m][n], 0, 0, 0);
        }

        if (t + 1 < NITER) {
            WRITE_BF16(ra, wA, cur ^ 1);
            LOAD_F32B(rb, gB, kn);
        }

        // kk = 1
        {
            bf16x8 af[8], bf[4];
#pragma unroll
            for (int m = 0; m < 8; m++) {
                int row = wr * 128 + m * 16 + l16;
                af[m] = *reinterpret_cast<const bf16x8*>(&As[row * 64 + xr1 * 8]);
            }
#pragma unroll
            for (int n = 0; n < 4; n++) {
                int row = wc * 64 + n * 16 + l16;
                bf[n] = *reinterpret_cast<const bf16x8*>(&Bs[row * 64 + xr1 * 8]);
            }
#pragma unroll
            for (int m = 0; m < 8; m++)
#pragma unroll
                for (int n = 0; n < 4; n++)
                    acc[m][n] = __builtin_amdgcn_mfma_f32_16x16x32_bf16(af[m], bf[n], acc[m][n], 0, 0, 0);
        }

        if (t + 1 < NITER) { CVT_WRITEB(rb, wB, cur ^ 1); }
        __syncthreads();
        cur ^= 1;
    }

    const int colbase = blockIdx.y * 256 + wc * 64;
#pragma unroll
    for (int m = 0; m < 8; m++) {
        int lr0 = m0 + wr * 128 + m * 16 + lq * 4;
#pragma unroll
        for (int j = 0; j < 4; j++) {
            int lr = lr0 + j;
            if (lr < n_e) {
                int tok = toks[lr];
                float w = weightv[base + lr];
#pragma unroll
                for (int n = 0; n < 4; n++) {
                    float v = acc[m][n][j] * w;
                    unsafeAtomicAdd(&out[(size_t)tok * Hdim + colbase + n * 16 + l16], v);
                }
            }
        }
    }
#undef LOAD_BF16
#undef WRITE_BF16
#undef LOAD_F32B
#undef CVT_WRITEB
}

// ---------------- launch ----------------

extern "C" void kernel_launch(void* const* d_in, const int* in_sizes, int n_in,
                              void* d_out, int out_size, void* d_ws, size_t ws_size,
                              hipStream_t stream) {
    const float* x = (const float*)d_in[0];
    const int* eidx = (const int*)d_in[1];
    const float* ewts = (const float*)d_in[2];
    const float* w13 = (const float*)d_in[3];
    const float* dproj = (const float*)d_in[4];
    float* out = (float*)d_out;

    // ws layout: ints block [0, 67840), then hact (16B-aligned)
    char* ws = (char*)d_ws;
    int* meta = (int*)ws;                       // [0..7] counts, [8..15] offsets
    int* token_id = meta + 64;                  // [NPAIR]
    float* weightv = (float*)(meta + 64 + NPAIR);
    int* chunkhist = meta + 64 + 2 * NPAIR;     // [32*NE]
    int* chunkbase = chunkhist + 256;           // [32*NE]
    bf16* hact = (bf16*)(ws + 67840);           // [NPAIR][Idim]

    hipMemsetAsync(d_out, 0, (size_t)out_size * sizeof(float), stream);

    k_bin1<<<32, 256, 0, stream>>>(eidx, chunkhist);
    k_bin2<<<1, 64, 0, stream>>>(meta, chunkhist, chunkbase);
    k_bin3<<<32, 256, 0, stream>>>(eidx, ewts, meta, chunkbase, token_id, weightv);

    k_gemm1<<<dim3(32, 11, 8), 512, 0, stream>>>(x, w13, meta, hact);
    k_gemm2<<<dim3(32, 8, 8), 512, 0, stream>>>(hact, dproj, meta, weightv, out);
}

// Round 7
// 354.514 us; speedup vs baseline: 4.4906x; 4.4906x over previous
//
#include <hip/hip_runtime.h>
#include <hip/hip_bf16.h>

// MoE SwiGLU: H=2048, I=1408, E=8, TOPK=2, T=4096 tokens (8192 pairs).
// R7 = R6 resubmitted unchanged (R6 bench died on infra: UnresponsiveContainer).
// R6 = R2 base (bf16 preconvert + global_load_lds + verified XOR swizzle)
// + XCD-chunked flat-grid swizzle (T1): one expert per XCD, so weight panels
// and token rows are L2-resident instead of being re-fetched from LLC 8-11x.

typedef __bf16 bf16;
typedef bf16 bf16x8 __attribute__((ext_vector_type(8)));
typedef float f32x4 __attribute__((ext_vector_type(4)));

constexpr int Hdim = 2048;
constexpr int Idim = 1408;
constexpr int NE = 8;
constexpr int TOPK = 2;
constexpr int NT = 4096;      // tokens
constexpr int NPAIR = 8192;   // T * TOPK
constexpr int BK = 64;

#define GLOAD16(G, L) __builtin_amdgcn_global_load_lds(                    \
    (const __attribute__((address_space(1))) void*)(G),                    \
    (__attribute__((address_space(3))) void*)(L), 16, 0, 0)

// ---------------- f32 -> bf16 convert (streaming) ----------------

__global__ void k_cvt(const float* __restrict__ src, bf16* __restrict__ dst, int n8) {
    int i = blockIdx.x * 256 + threadIdx.x;
    if (i >= n8) return;
    f32x4 a = *reinterpret_cast<const f32x4*>(src + (size_t)i * 8);
    f32x4 b = *reinterpret_cast<const f32x4*>(src + (size_t)i * 8 + 4);
    bf16x8 v;
#pragma unroll
    for (int j = 0; j < 4; j++) { v[j] = (bf16)a[j]; v[4 + j] = (bf16)b[j]; }
    *reinterpret_cast<bf16x8*>(dst + (size_t)i * 8) = v;
}

// ---------------- binning (deterministic) ----------------

__global__ void k_bin1(const int* __restrict__ eidx, int* __restrict__ chunkhist) {
    __shared__ int h[NE];
    int t = threadIdx.x;
    if (t < NE) h[t] = 0;
    __syncthreads();
    int p = blockIdx.x * 256 + t;
    atomicAdd(&h[eidx[p]], 1);
    __syncthreads();
    if (t < NE) chunkhist[blockIdx.x * NE + t] = h[t];
}

__global__ void k_bin2(int* __restrict__ meta, const int* __restrict__ chunkhist,
                       int* __restrict__ chunkbase) {
    if (threadIdx.x == 0) {
        int counts[NE];
        for (int e = 0; e < NE; e++) counts[e] = 0;
        for (int b = 0; b < 32; b++)
            for (int e = 0; e < NE; e++) {
                chunkbase[b * NE + e] = counts[e];
                counts[e] += chunkhist[b * NE + e];
            }
        int acc = 0;
        for (int e = 0; e < NE; e++) {
            meta[e] = counts[e];      // counts
            meta[8 + e] = acc;        // exclusive offsets
            acc += counts[e];
        }
    }
}

__global__ void k_bin3(const int* __restrict__ eidx, const float* __restrict__ wts,
                       const int* __restrict__ meta, const int* __restrict__ chunkbase,
                       int* __restrict__ token_id, float* __restrict__ weightv) {
    __shared__ int earr[256];
    int t = threadIdx.x;
    int p = blockIdx.x * 256 + t;
    int e = eidx[p];
    earr[t] = e;
    __syncthreads();
    int rank = 0;
    for (int q = 0; q < t; q++) rank += (earr[q] == e) ? 1 : 0;
    int pos = meta[8 + e] + chunkbase[blockIdx.x * NE + e] + rank;
    token_id[pos] = p / TOPK;
    weightv[pos] = wts[p];
}

// ---------------- GEMM1: gu = X_e * w13[e]^T, fused SwiGLU ----------------
// Flat grid 5632 = 64 m-slots x 11 y-tiles x 8 experts. XCD-chunk swizzle:
// work = (flat%8)*704 + flat/8 -> XCD k runs groups [11k, 11k+11) = expert k.

__global__ __launch_bounds__(256, 2) void k_gemm1(
    const bf16* __restrict__ xb, const bf16* __restrict__ w13b,
    const int* __restrict__ meta, bf16* __restrict__ hact) {
    const int flat = blockIdx.x;
    const int work = (flat & 7) * 704 + (flat >> 3);
    const int mslot = work & 63;
    const int grp = work >> 6;        // [0,88)
    const int e = grp / 11;
    const int ytile = grp - e * 11;

    const int n_e = meta[e];
    const int m0 = mslot * 128;
    if (m0 >= n_e) return;
    const int base = meta[8 + e];
    const int* toks = (const int*)(meta + 64) + base;
    const bf16* wg = w13b + (size_t)e * (2 * Idim) * Hdim + (size_t)(ytile * 128) * Hdim;
    const bf16* wu = wg + (size_t)Idim * Hdim;

    __shared__ bf16 As[128 * 64];
    __shared__ bf16 Bg[128 * 64];
    __shared__ bf16 Bu[128 * 64];

    const int tid = threadIdx.x;
    const int lane = tid & 63;
    const int wid = tid >> 6;
    const int wr = wid >> 1, wc = wid & 1;
    const int l16 = lane & 15, lq = lane >> 4;

    // staging: 1024 slots of 16B per tile, 4 rounds x 256 threads.
    // LDS dest LINEAR; global source pre-swizzled: LDS seg s of row r holds
    // global seg s^(r&7).
    const bf16* gA[4];
    const bf16* gG[4];
    const bf16* gU[4];
    int lo[4];
#pragma unroll
    for (int r = 0; r < 4; r++) {
        int sid = r * 256 + tid;
        int row = sid >> 3, seg = sid & 7;
        int ss = seg ^ (row & 7);
        lo[r] = (r * 256 + (tid & ~63)) * 16;   // wave-uniform LDS byte base
        int rr = m0 + row;
        if (rr >= n_e) rr = n_e - 1;            // clamp keeps reads in-bounds
        gA[r] = xb + (size_t)toks[rr] * Hdim + ss * 8;
        gG[r] = wg + (size_t)row * Hdim + ss * 8;
        gU[r] = wu + (size_t)row * Hdim + ss * 8;
    }

    f32x4 accg[4][4], accu[4][4];
#pragma unroll
    for (int m = 0; m < 4; m++)
#pragma unroll
        for (int n = 0; n < 4; n++) {
            accg[m][n] = f32x4{0.f, 0.f, 0.f, 0.f};
            accu[m][n] = f32x4{0.f, 0.f, 0.f, 0.f};
        }

    for (int k0 = 0; k0 < Hdim; k0 += BK) {
        __syncthreads();
#pragma unroll
        for (int r = 0; r < 4; r++) {
            GLOAD16(gA[r] + k0, (char*)As + lo[r]);
            GLOAD16(gG[r] + k0, (char*)Bg + lo[r]);
            GLOAD16(gU[r] + k0, (char*)Bu + lo[r]);
        }
        __syncthreads();
#pragma unroll
        for (int kk = 0; kk < 2; ++kk) {
            bf16x8 af[4], bgf[4], buf_[4];
#pragma unroll
            for (int m = 0; m < 4; m++) {
                int row = wr * 64 + m * 16 + l16;
                int s = (kk * 4 + lq) ^ (row & 7);
                af[m] = *reinterpret_cast<const bf16x8*>(&As[row * 64 + s * 8]);
            }
#pragma unroll
            for (int n = 0; n < 4; n++) {
                int row = wc * 64 + n * 16 + l16;
                int s = (kk * 4 + lq) ^ (row & 7);
                bgf[n] = *reinterpret_cast<const bf16x8*>(&Bg[row * 64 + s * 8]);
                buf_[n] = *reinterpret_cast<const bf16x8*>(&Bu[row * 64 + s * 8]);
            }
#pragma unroll
            for (int m = 0; m < 4; m++)
#pragma unroll
                for (int n = 0; n < 4; n++) {
                    accg[m][n] = __builtin_amdgcn_mfma_f32_16x16x32_bf16(af[m], bgf[n], accg[m][n], 0, 0, 0);
                    accu[m][n] = __builtin_amdgcn_mfma_f32_16x16x32_bf16(af[m], buf_[n], accu[m][n], 0, 0, 0);
                }
        }
    }

    // epilogue: silu(g)*u -> hact. C layout: col=lane&15, row=(lane>>4)*4+reg
    const int colbase = ytile * 128 + wc * 64;
#pragma unroll
    for (int m = 0; m < 4; m++) {
        int lr0 = m0 + wr * 64 + m * 16 + lq * 4;
#pragma unroll
        for (int j = 0; j < 4; j++) {
            int lr = lr0 + j;
            if (lr < n_e) {
                size_t rowoff = (size_t)(base + lr) * Idim;
#pragma unroll
                for (int n = 0; n < 4; n++) {
                    float g = accg[m][n][j], u = accu[m][n][j];
                    float v = (g / (1.f + __expf(-g))) * u;
                    hact[rowoff + colbase + n * 16 + l16] = (bf16)v;
                }
            }
        }
    }
}

// ---------------- GEMM2: y = hact * down_proj[e]^T, weighted scatter-add ----------------
// Flat grid 8192 = 64 m-slots x 16 y-tiles x 8 experts. XCD-chunk swizzle:
// work = (flat%8)*1024 + flat/8 -> XCD k runs expert k's 16 y-tiles.

__global__ __launch_bounds__(256, 2) void k_gemm2(
    const bf16* __restrict__ hact, const bf16* __restrict__ dpb,
    const int* __restrict__ meta, const float* __restrict__ weightv,
    float* __restrict__ out) {
    const int flat = blockIdx.x;
    const int work = (flat & 7) * 1024 + (flat >> 3);
    const int mslot = work & 63;
    const int grp = work >> 6;        // [0,128)
    const int e = grp >> 4;
    const int ytile = grp & 15;

    const int n_e = meta[e];
    const int m0 = mslot * 128;
    if (m0 >= n_e) return;
    const int base = meta[8 + e];
    const int* toks = (const int*)(meta + 64) + base;
    const bf16* wb = dpb + (size_t)e * Hdim * Idim + (size_t)(ytile * 128) * Idim;

    __shared__ bf16 As[128 * 64];
    __shared__ bf16 Bs[128 * 64];

    const int tid = threadIdx.x;
    const int lane = tid & 63;
    const int wid = tid >> 6;
    const int wr = wid >> 1, wc = wid & 1;
    const int l16 = lane & 15, lq = lane >> 4;

    const bf16* gA[4];
    const bf16* gB[4];
    int lo[4];
#pragma unroll
    for (int r = 0; r < 4; r++) {
        int sid = r * 256 + tid;
        int row = sid >> 3, seg = sid & 7;
        int ss = seg ^ (row & 7);
        lo[r] = (r * 256 + (tid & ~63)) * 16;
        int rr = m0 + row;
        if (rr >= n_e) rr = n_e - 1;
        gA[r] = hact + (size_t)(base + rr) * Idim + ss * 8;
        gB[r] = wb + (size_t)row * Idim + ss * 8;
    }

    f32x4 acc[4][4];
#pragma unroll
    for (int m = 0; m < 4; m++)
#pragma unroll
        for (int n = 0; n < 4; n++) acc[m][n] = f32x4{0.f, 0.f, 0.f, 0.f};

    for (int k0 = 0; k0 < Idim; k0 += BK) {
        __syncthreads();
#pragma unroll
        for (int r = 0; r < 4; r++) {
            GLOAD16(gA[r] + k0, (char*)As + lo[r]);
            GLOAD16(gB[r] + k0, (char*)Bs + lo[r]);
        }
        __syncthreads();
#pragma unroll
        for (int kk = 0; kk < 2; ++kk) {
            bf16x8 af[4], bf_[4];
#pragma unroll
            for (int m = 0; m < 4; m++) {
                int row = wr * 64 + m * 16 + l16;
                int s = (kk * 4 + lq) ^ (row & 7);
                af[m] = *reinterpret_cast<const bf16x8*>(&As[row * 64 + s * 8]);
            }
#pragma unroll
            for (int n = 0; n < 4; n++) {
                int row = wc * 64 + n * 16 + l16;
                int s = (kk * 4 + lq) ^ (row & 7);
                bf_[n] = *reinterpret_cast<const bf16x8*>(&Bs[row * 64 + s * 8]);
            }
#pragma unroll
            for (int m = 0; m < 4; m++)
#pragma unroll
                for (int n = 0; n < 4; n++)
                    acc[m][n] = __builtin_amdgcn_mfma_f32_16x16x32_bf16(af[m], bf_[n], acc[m][n], 0, 0, 0);
        }
    }

    const int colbase = ytile * 128 + wc * 64;
#pragma unroll
    for (int m = 0; m < 4; m++) {
        int lr0 = m0 + wr * 64 + m * 16 + lq * 4;
#pragma unroll
        for (int j = 0; j < 4; j++) {
            int lr = lr0 + j;
            if (lr < n_e) {
                int tok = toks[lr];
                float w = weightv[base + lr];
#pragma unroll
                for (int n = 0; n < 4; n++) {
                    float v = acc[m][n][j] * w;
                    unsafeAtomicAdd(&out[(size_t)tok * Hdim + colbase + n * 16 + l16], v);
                }
            }
        }
    }
}

// ---------------- launch ----------------

extern "C" void kernel_launch(void* const* d_in, const int* in_sizes, int n_in,
                              void* d_out, int out_size, void* d_ws, size_t ws_size,
                              hipStream_t stream) {
    const float* x = (const float*)d_in[0];
    const int* eidx = (const int*)d_in[1];
    const float* ewts = (const float*)d_in[2];
    const float* w13 = (const float*)d_in[3];
    const float* dproj = (const float*)d_in[4];
    float* out = (float*)d_out;

    // ws layout (bytes): ints block [0, 67840), then bf16 buffers (16B-aligned)
    char* ws = (char*)d_ws;
    int* meta = (int*)ws;                       // [0..7] counts, [8..15] offsets
    int* token_id = meta + 64;                  // [NPAIR]
    float* weightv = (float*)(meta + 64 + NPAIR);
    int* chunkhist = meta + 64 + 2 * NPAIR;     // [32*NE]
    int* chunkbase = chunkhist + 256;           // [32*NE]
    bf16* xb = (bf16*)(ws + 67840);             // [NT][Hdim]
    bf16* w13b = xb + (size_t)NT * Hdim;        // [NE][2*Idim][Hdim]
    bf16* dpb = w13b + (size_t)NE * 2 * Idim * Hdim;  // [NE][Hdim][Idim]
    bf16* hact = dpb + (size_t)NE * Hdim * Idim;      // [NPAIR][Idim]

    hipMemsetAsync(d_out, 0, (size_t)out_size * sizeof(float), stream);

    const int nx8 = NT * Hdim / 8;                    // 1048576
    const int nw8 = NE * 2 * Idim * Hdim / 8;         // 5767168
    const int nd8 = NE * Hdim * Idim / 8;             // 2883584
    k_cvt<<<(nx8 + 255) / 256, 256, 0, stream>>>(x, xb, nx8);
    k_cvt<<<(nw8 + 255) / 256, 256, 0, stream>>>(w13, w13b, nw8);
    k_cvt<<<(nd8 + 255) / 256, 256, 0, stream>>>(dproj, dpb, nd8);

    k_bin1<<<32, 256, 0, stream>>>(eidx, chunkhist);
    k_bin2<<<1, 64, 0, stream>>>(meta, chunkhist, chunkbase);
    k_bin3<<<32, 256, 0, stream>>>(eidx, ewts, meta, chunkbase, token_id, weightv);

    k_gemm1<<<5632, 256, 0, stream>>>(xb, w13b, meta, hact);
    k_gemm2<<<8192, 256, 0, stream>>>(hact, dpb, meta, weightv, out);
}